// Round 1
// baseline (46.184 us; speedup 1.0000x reference)
//
#include <hip/hip_runtime.h>

#define UNITS 1024
#define DIN   2048
#define KCONN 16
#define BATCH 4096
#define BB    8   // batch rows staged per block in kernel 2

// ---------------------------------------------------------------------------
// Kernel 1: per-unit top-16 of P = D + GN, plus sign(W) coefficients.
// One wave (64 lanes) per unit; 4 units per 256-thread block.
// ---------------------------------------------------------------------------
__global__ __launch_bounds__(256) void topk_sel_kernel(
    const float* __restrict__ Dl, const float* __restrict__ GN,
    const float* __restrict__ W, int* __restrict__ selIdx,
    float* __restrict__ selC) {
  __shared__ float P[4][DIN];          // 32 KB
  __shared__ int chosen[4][KCONN];
  const int lane = threadIdx.x & 63;
  const int wv   = threadIdx.x >> 6;
  const int u    = blockIdx.x * 4 + wv;

  const float4* D4 = (const float4*)(Dl + (size_t)u * DIN);
  const float4* G4 = (const float4*)(GN + (size_t)u * DIN);
  float4* P4 = (float4*)P[wv];
#pragma unroll
  for (int i = 0; i < DIN / 4 / 64; ++i) {   // 8 float4 per lane, coalesced
    int e = i * 64 + lane;
    float4 d = D4[e], g = G4[e];
    P4[e] = make_float4(d.x + g.x, d.y + g.y, d.z + g.z, d.w + g.w);
  }
  __syncthreads();

  for (int it = 0; it < KCONN; ++it) {
    // per-lane scan of its own column (bank = lane%32 -> 2-way, conflict-free)
    float best = -INFINITY;
    int   bi   = DIN;
#pragma unroll
    for (int i = 0; i < DIN / 64; ++i) {
      float v = P[wv][i * 64 + lane];
      if (v > best) { best = v; bi = i * 64 + lane; }   // ascending scan: ties keep lower idx
    }
    // 64-lane butterfly argmax, tie -> smaller index (matches top_k tie order)
#pragma unroll
    for (int off = 1; off < 64; off <<= 1) {
      float ov = __shfl_xor(best, off, 64);
      int   oi = __shfl_xor(bi, off, 64);
      if (ov > best || (ov == best && oi < bi)) { best = ov; bi = oi; }
    }
    // owner lane invalidates its own element (same-lane dep -> safe without barrier)
    if (lane == (bi & 63)) P[wv][bi] = -INFINITY;
    if (lane == 0) chosen[wv][it] = bi;
  }
  __syncthreads();

  if (lane < KCONN) {
    int gi = chosen[wv][lane];
    float w = W[(size_t)u * DIN + gi];
    float c = (w > 0.0f) ? 1.0f : ((w < 0.0f) ? -1.0f : 0.0f);  // jnp.sign semantics
    selIdx[u * KCONN + lane] = gi;
    selC[u * KCONN + lane]   = c;
  }
}

// ---------------------------------------------------------------------------
// Kernel 2: y[b,u] = sum_j c[u][j] * x[b, idx[u][j]]
// Block stages BB=8 rows of x in LDS (64 KB); each thread does 4 units x 8 rows.
// ---------------------------------------------------------------------------
__global__ __launch_bounds__(256) void gather_mm_kernel(
    const float* __restrict__ x, const int* __restrict__ selIdx,
    const float* __restrict__ selC, float* __restrict__ y) {
  __shared__ float xs[BB * DIN];       // 64 KB -> 2 blocks/CU
  const int tid = threadIdx.x;
  const size_t b0 = (size_t)blockIdx.x * BB;

  // stage 8 rows, fully coalesced float4
  const float4* xg = (const float4*)(x + b0 * DIN);
  float4* xs4 = (float4*)xs;
#pragma unroll
  for (int it = 0; it < (BB * DIN / 4) / 256; ++it) {  // 16 iters
    int f = it * 256 + tid;
    xs4[f] = xg[f];
  }
  __syncthreads();

#pragma unroll 1
  for (int uu = 0; uu < UNITS / 256; ++uu) {           // 4 units per thread
    const int u = uu * 256 + tid;
    int   idx[KCONN];
    float c[KCONN];
    const int4*   I4 = (const int4*)(selIdx + u * KCONN);
    const float4* C4 = (const float4*)(selC + u * KCONN);
#pragma unroll
    for (int q = 0; q < KCONN / 4; ++q) {
      int4   a = I4[q];
      float4 b = C4[q];
      idx[q * 4 + 0] = a.x; idx[q * 4 + 1] = a.y;
      idx[q * 4 + 2] = a.z; idx[q * 4 + 3] = a.w;
      c[q * 4 + 0] = b.x; c[q * 4 + 1] = b.y;
      c[q * 4 + 2] = b.z; c[q * 4 + 3] = b.w;
    }
    float acc[BB];
#pragma unroll
    for (int b = 0; b < BB; ++b) acc[b] = 0.0f;
#pragma unroll
    for (int j = 0; j < KCONN; ++j) {
      const int   d  = idx[j];
      const float cj = c[j];
#pragma unroll
      for (int b = 0; b < BB; ++b)
        acc[b] += cj * xs[b * DIN + d];
    }
#pragma unroll
    for (int b = 0; b < BB; ++b)
      y[(b0 + b) * UNITS + u] = acc[b];   // consecutive lanes -> consecutive u
  }
}

// ---------------------------------------------------------------------------
extern "C" void kernel_launch(void* const* d_in, const int* in_sizes, int n_in,
                              void* d_out, int out_size, void* d_ws, size_t ws_size,
                              hipStream_t stream) {
  const float* x  = (const float*)d_in[0];   // [4096, 2048]
  const float* W  = (const float*)d_in[1];   // [1024, 2048]
  const float* Dl = (const float*)d_in[2];   // [1024, 2048]
  const float* GN = (const float*)d_in[3];   // [1, 1024, 2048]
  // d_in[4] = k (compile-time 16)
  float* y = (float*)d_out;                  // [4096, 1024]

  int*   selIdx = (int*)d_ws;                                  // 1024*16 ints
  float* selC   = (float*)((char*)d_ws + UNITS * KCONN * sizeof(int));

  topk_sel_kernel<<<UNITS / 4, 256, 0, stream>>>(Dl, GN, W, selIdx, selC);
  gather_mm_kernel<<<BATCH / BB, 256, 0, stream>>>(x, selIdx, selC, y);
}

// Round 2
// 38.086 us; speedup vs baseline: 1.2126x; 1.2126x over previous
//
#include <hip/hip_runtime.h>
#include <hip/hip_bf16.h>

#define UNITS 1024
#define DIN   2048
#define KCONN 16
#define BATCH 4096
#define BB    8   // batch rows per block in kernel 2

// ---------------------------------------------------------------------------
// Kernel 1: per-unit top-16 of P = D + GN, plus sign(W) coefficients.
// One wave (64 lanes) per unit; 4 units per 256-thread block.
// Emits PRE-SWIZZLED LDS byte offsets so kernel 2's gather needs no addr VALU.
// ---------------------------------------------------------------------------
__global__ __launch_bounds__(256) void topk_sel_kernel(
    const float* __restrict__ Dl, const float* __restrict__ GN,
    const float* __restrict__ W, int* __restrict__ selOff,
    float* __restrict__ selC) {
  __shared__ float P[4][DIN];          // 32 KB
  __shared__ int chosen[4][KCONN];
  const int lane = threadIdx.x & 63;
  const int wv   = threadIdx.x >> 6;
  const int u    = blockIdx.x * 4 + wv;

  const float4* D4 = (const float4*)(Dl + (size_t)u * DIN);
  const float4* G4 = (const float4*)(GN + (size_t)u * DIN);
  float4* P4 = (float4*)P[wv];
#pragma unroll
  for (int i = 0; i < DIN / 4 / 64; ++i) {   // 8 float4 per lane, coalesced
    int e = i * 64 + lane;
    float4 d = D4[e], g = G4[e];
    P4[e] = make_float4(d.x + g.x, d.y + g.y, d.z + g.z, d.w + g.w);
  }
  __syncthreads();

  for (int it = 0; it < KCONN; ++it) {
    float best = -INFINITY;
    int   bi   = DIN;
#pragma unroll
    for (int i = 0; i < DIN / 64; ++i) {
      float v = P[wv][i * 64 + lane];   // bank = lane%32 -> 2-way, free
      if (v > best) { best = v; bi = i * 64 + lane; }
    }
#pragma unroll
    for (int off = 1; off < 64; off <<= 1) {  // butterfly argmax, tie -> low idx
      float ov = __shfl_xor(best, off, 64);
      int   oi = __shfl_xor(bi, off, 64);
      if (ov > best || (ov == best && oi < bi)) { best = ov; bi = oi; }
    }
    if (lane == (bi & 63)) P[wv][bi] = -INFINITY;  // owner-lane invalidate
    if (lane == 0) chosen[wv][it] = bi;
  }
  __syncthreads();

  if (lane < KCONN) {
    int gi = chosen[wv][lane];
    float w = W[(size_t)u * DIN + gi];
    float c = (w > 0.0f) ? 1.0f : ((w < 0.0f) ? -1.0f : 0.0f);
    int sd = gi ^ ((gi >> 3) & 7);            // chunk swizzle (matches staging)
    selOff[u * KCONN + lane] = sd << 4;       // byte offset of 16B chunk
    selC[u * KCONN + lane]   = c;
  }
}

// ---------------------------------------------------------------------------
// Kernel 2: y[b,u] = sum_j c[u][j] * x[b, idx[u][j]]
// LDS tile is TRANSPOSED + bf16-packed: xs[sd] = 16B chunk of 8 batch values
// for feature d. One ds_read_b128 per (unit, j) serves all 8 batches.
// 512 threads (8 waves), 2 units per thread, 2 blocks/CU.
// ---------------------------------------------------------------------------
__global__ __launch_bounds__(512) void gather_mm_kernel(
    const float* __restrict__ x, const int* __restrict__ selOff,
    const float* __restrict__ selC, float* __restrict__ y) {
  __shared__ uint4 xs[DIN];            // 32 KB, swizzled chunk order
  const int t = threadIdx.x;
  const size_t b0 = (size_t)blockIdx.x * BB;

  // ---- stage: transpose 8 rows of x into bf16-packed chunks ----
  // thread t owns row pair (2m, 2m+1), m = t&3; d-chunks q = t>>2 (+128 per pass)
  {
    const int m  = t & 3;
    const int qb = t >> 2;
    const float* r0 = x + (b0 + 2 * m) * DIN;
    const float* r1 = r0 + DIN;
    unsigned* xsw = (unsigned*)xs;
#pragma unroll
    for (int p = 0; p < 4; ++p) {
      const int d0 = (p * 128 + qb) * 4;
      float4 a = *(const float4*)(r0 + d0);
      float4 b = *(const float4*)(r1 + d0);
      float av[4] = {a.x, a.y, a.z, a.w};
      float bv[4] = {b.x, b.y, b.z, b.w};
#pragma unroll
      for (int j = 0; j < 4; ++j) {
        const int d  = d0 + j;
        const int sd = d ^ ((d >> 3) & 7);
        __hip_bfloat16 hl = __float2bfloat16(av[j]);   // RNE
        __hip_bfloat16 hh = __float2bfloat16(bv[j]);
        unsigned lo = *(const unsigned short*)&hl;
        unsigned hi = *(const unsigned short*)&hh;
        // word m of chunk sd holds batches (2m, 2m+1); banks 2-way -> free
        xsw[sd * 4 + m] = lo | (hi << 16);
      }
    }
  }
  __syncthreads();

  // ---- gather + accumulate ----
  const char* xsb = (const char*)xs;
#pragma unroll 1
  for (int uu = 0; uu < UNITS / 512; ++uu) {   // 2 units per thread
    const int u = uu * 512 + t;
    int   off[KCONN];
    float c[KCONN];
    const int4*   I4 = (const int4*)(selOff + u * KCONN);
    const float4* C4 = (const float4*)(selC + u * KCONN);
#pragma unroll
    for (int q = 0; q < KCONN / 4; ++q) {
      int4   a = I4[q];
      float4 b = C4[q];
      off[q * 4 + 0] = a.x; off[q * 4 + 1] = a.y;
      off[q * 4 + 2] = a.z; off[q * 4 + 3] = a.w;
      c[q * 4 + 0] = b.x; c[q * 4 + 1] = b.y;
      c[q * 4 + 2] = b.z; c[q * 4 + 3] = b.w;
    }
    float acc[BB];
#pragma unroll
    for (int b = 0; b < BB; ++b) acc[b] = 0.0f;
#pragma unroll
    for (int j = 0; j < KCONN; ++j) {
      uint4 v = *(const uint4*)(xsb + off[j]);       // ds_read_b128
      const float cj = c[j];
      acc[0] = fmaf(cj, __uint_as_float(v.x << 16),        acc[0]);
      acc[1] = fmaf(cj, __uint_as_float(v.x & 0xffff0000u), acc[1]);
      acc[2] = fmaf(cj, __uint_as_float(v.y << 16),        acc[2]);
      acc[3] = fmaf(cj, __uint_as_float(v.y & 0xffff0000u), acc[3]);
      acc[4] = fmaf(cj, __uint_as_float(v.z << 16),        acc[4]);
      acc[5] = fmaf(cj, __uint_as_float(v.z & 0xffff0000u), acc[5]);
      acc[6] = fmaf(cj, __uint_as_float(v.w << 16),        acc[6]);
      acc[7] = fmaf(cj, __uint_as_float(v.w & 0xffff0000u), acc[7]);
    }
#pragma unroll
    for (int b = 0; b < BB; ++b)
      y[(b0 + b) * UNITS + u] = acc[b];    // consecutive lanes -> consecutive u
  }
}

// ---------------------------------------------------------------------------
extern "C" void kernel_launch(void* const* d_in, const int* in_sizes, int n_in,
                              void* d_out, int out_size, void* d_ws, size_t ws_size,
                              hipStream_t stream) {
  const float* x  = (const float*)d_in[0];   // [4096, 2048]
  const float* W  = (const float*)d_in[1];   // [1024, 2048]
  const float* Dl = (const float*)d_in[2];   // [1024, 2048]
  const float* GN = (const float*)d_in[3];   // [1, 1024, 2048]
  float* y = (float*)d_out;                  // [4096, 1024]

  int*   selOff = (int*)d_ws;                                  // 1024*16 ints
  float* selC   = (float*)((char*)d_ws + UNITS * KCONN * sizeof(int));

  topk_sel_kernel<<<UNITS / 4, 256, 0, stream>>>(Dl, GN, W, selOff, selC);
  gather_mm_kernel<<<BATCH / BB, 512, 0, stream>>>(x, selOff, selC, y);
}

// Round 3
// 32.707 us; speedup vs baseline: 1.4120x; 1.1644x over previous
//
#include <hip/hip_runtime.h>
#include <hip/hip_bf16.h>

#define UNITS 1024
#define DIN   2048
#define KCONN 16
#define BATCH 4096
#define BB    8   // batch rows per tile in kernel 2

// ---------------------------------------------------------------------------
// Kernel 1: per-unit top-16 of P = D + GN, plus sign(W) coefficients.
// One wave per unit, 4 units / 256-thread block. Wave argmax via DPP
// (row_shr 1/2/4/8 + row_bcast15/31) on (monotone u32 key, index) — pure
// VALU latency instead of 12 serial ds_bpermutes per iteration.
// Emits the LDS *chunk index* (pre-swizzled) for kernel 2.
// ---------------------------------------------------------------------------
__global__ __launch_bounds__(256) void topk_sel_kernel(
    const float* __restrict__ Dl, const float* __restrict__ GN,
    const float* __restrict__ W, int* __restrict__ selCi,
    float* __restrict__ selC) {
  __shared__ float P[4][DIN];          // 32 KB
  __shared__ int chosen[4][KCONN];
  const int lane = threadIdx.x & 63;
  const int wv   = threadIdx.x >> 6;
  const int u    = blockIdx.x * 4 + wv;

  const float4* D4 = (const float4*)(Dl + (size_t)u * DIN);
  const float4* G4 = (const float4*)(GN + (size_t)u * DIN);
  float4* P4 = (float4*)P[wv];
#pragma unroll
  for (int i = 0; i < DIN / 4 / 64; ++i) {   // 8 float4 per lane, coalesced
    int e = i * 64 + lane;
    float4 d = D4[e], g = G4[e];
    P4[e] = make_float4(d.x + g.x, d.y + g.y, d.z + g.z, d.w + g.w);
  }
  __syncthreads();

  for (int it = 0; it < KCONN; ++it) {
    // per-lane scan (ds_read_b32, bank = lane%32 -> 2-way, free)
    float best = -INFINITY;
    int   bi   = 0;
#pragma unroll
    for (int i = 0; i < DIN / 64; ++i) {
      float v = P[wv][i * 64 + lane];
      if (v > best) { best = v; bi = i * 64 + lane; }   // first-wins on tie
    }
    // monotone u32 key: unsigned compare == float compare
    unsigned b  = __float_as_uint(best);
    unsigned kv = b ^ (((int)b < 0) ? 0xFFFFFFFFu : 0x80000000u);
    int id = bi;
    // wave64 argmax reduce via DPP; invalid/masked lanes keep old (identity)
#define DSTEP(CTRL, RM) { \
    unsigned kv2 = (unsigned)__builtin_amdgcn_update_dpp((int)kv, (int)kv, CTRL, RM, 0xF, false); \
    int id2 = __builtin_amdgcn_update_dpp(id, id, CTRL, RM, 0xF, false); \
    bool tk = (kv2 > kv) || ((kv2 == kv) && (id2 < id)); \
    kv = tk ? kv2 : kv; id = tk ? id2 : id; }
    DSTEP(0x111, 0xF)   // row_shr:1
    DSTEP(0x112, 0xF)   // row_shr:2
    DSTEP(0x114, 0xF)   // row_shr:4
    DSTEP(0x118, 0xF)   // row_shr:8
    DSTEP(0x142, 0xA)   // row_bcast:15 -> rows 1,3
    DSTEP(0x143, 0xC)   // row_bcast:31 -> rows 2,3
#undef DSTEP
    int widx = __builtin_amdgcn_readlane(id, 63);       // global argmax index
    if (lane == (widx & 63)) P[wv][widx] = -INFINITY;   // owner invalidates
    if (lane == 0) chosen[wv][it] = widx;
  }

  if (lane < KCONN) {
    int gi = chosen[wv][lane];
    float w = W[(size_t)u * DIN + gi];
    float c = (w > 0.0f) ? 1.0f : ((w < 0.0f) ? -1.0f : 0.0f);
    selCi[u * KCONN + lane] = gi ^ ((gi >> 3) & 7);   // swizzled CHUNK index
    selC[u * KCONN + lane]  = c;
  }
}

// ---------------------------------------------------------------------------
// Kernel 2: y[b,u] = sum_j c[u][j] * x[b, idx[u][j]]
// LDS tile: xs[chunk] = 16B of 8 bf16 batch values for one feature, chunk
// XOR-swizzled. Typed __shared__ uint4 indexing everywhere -> guaranteed
// ds_read_b128 / ds_write_b128. Sel data prefetched before staging.
// 512 threads, grid 512 (2 blocks/CU), 2 units/thread fully unrolled.
// ---------------------------------------------------------------------------
__global__ __launch_bounds__(512) void gather_mm_kernel(
    const float* __restrict__ x, const int* __restrict__ selCi,
    const float* __restrict__ selC, float* __restrict__ y) {
  __shared__ uint4 xs[DIN];            // 32 KB
  const int t = threadIdx.x;
  const size_t b0 = (size_t)blockIdx.x * BB;

  // ---- prefetch sel for units t and t+512 (in flight during staging) ----
  const int4*   Ia = (const int4*)(selCi + t * KCONN);
  const int4*   Ib = (const int4*)(selCi + (t + 512) * KCONN);
  const float4* Ca = (const float4*)(selC + t * KCONN);
  const float4* Cb = (const float4*)(selC + (t + 512) * KCONN);
  int4   i0 = Ia[0], i1 = Ia[1], i2 = Ia[2], i3 = Ia[3];
  int4   i4 = Ib[0], i5 = Ib[1], i6 = Ib[2], i7 = Ib[3];
  float4 c0 = Ca[0], c1 = Ca[1], c2 = Ca[2], c3 = Ca[3];
  float4 c4 = Cb[0], c5 = Cb[1], c6 = Cb[2], c7 = Cb[3];

  // ---- stage: thread t owns features 4t..4t+3; builds whole 16B chunks ----
  const float* xb = x + b0 * DIN + 4 * t;
  float4 r0 = *(const float4*)(xb + 0 * DIN);
  float4 r1 = *(const float4*)(xb + 1 * DIN);
  float4 r2 = *(const float4*)(xb + 2 * DIN);
  float4 r3 = *(const float4*)(xb + 3 * DIN);
  float4 r4 = *(const float4*)(xb + 4 * DIN);
  float4 r5 = *(const float4*)(xb + 5 * DIN);
  float4 r6 = *(const float4*)(xb + 6 * DIN);
  float4 r7 = *(const float4*)(xb + 7 * DIN);

#define PK2(LO, HI) ({ __hip_bfloat16 l_ = __float2bfloat16(LO), h_ = __float2bfloat16(HI); \
  (unsigned)(*(unsigned short*)&l_) | ((unsigned)(*(unsigned short*)&h_) << 16); })
#define MKCH(J, C) { const int d_ = 4 * t + (J); const int sd_ = d_ ^ ((d_ >> 3) & 7); \
  uint4 ch_; ch_.x = PK2(r0.C, r1.C); ch_.y = PK2(r2.C, r3.C); \
  ch_.z = PK2(r4.C, r5.C); ch_.w = PK2(r6.C, r7.C); xs[sd_] = ch_; }
  MKCH(0, x) MKCH(1, y) MKCH(2, z) MKCH(3, w)
#undef MKCH
#undef PK2
  __syncthreads();

  // ---- gather + accumulate, fully static ----
#define BL(w) __uint_as_float((w) << 16)
#define BH(w) __uint_as_float((w) & 0xffff0000u)
#define GJ(CI, CC) { uint4 v_ = xs[CI]; const float cc_ = (CC); \
  a0 = fmaf(cc_, BL(v_.x), a0); a1 = fmaf(cc_, BH(v_.x), a1); \
  a2 = fmaf(cc_, BL(v_.y), a2); a3 = fmaf(cc_, BH(v_.y), a3); \
  a4 = fmaf(cc_, BL(v_.z), a4); a5 = fmaf(cc_, BH(v_.z), a5); \
  a6 = fmaf(cc_, BL(v_.w), a6); a7 = fmaf(cc_, BH(v_.w), a7); }
#define UNIT(IA, IB, IC, ID, CA, CB, CC_, CD, U) { \
  float a0 = 0, a1 = 0, a2 = 0, a3 = 0, a4 = 0, a5 = 0, a6 = 0, a7 = 0; \
  GJ(IA.x, CA.x) GJ(IA.y, CA.y) GJ(IA.z, CA.z) GJ(IA.w, CA.w) \
  GJ(IB.x, CB.x) GJ(IB.y, CB.y) GJ(IB.z, CB.z) GJ(IB.w, CB.w) \
  GJ(IC.x, CC_.x) GJ(IC.y, CC_.y) GJ(IC.z, CC_.z) GJ(IC.w, CC_.w) \
  GJ(ID.x, CD.x) GJ(ID.y, CD.y) GJ(ID.z, CD.z) GJ(ID.w, CD.w) \
  const int u_ = (U); \
  y[(b0 + 0) * UNITS + u_] = a0; y[(b0 + 1) * UNITS + u_] = a1; \
  y[(b0 + 2) * UNITS + u_] = a2; y[(b0 + 3) * UNITS + u_] = a3; \
  y[(b0 + 4) * UNITS + u_] = a4; y[(b0 + 5) * UNITS + u_] = a5; \
  y[(b0 + 6) * UNITS + u_] = a6; y[(b0 + 7) * UNITS + u_] = a7; }

  UNIT(i0, i1, i2, i3, c0, c1, c2, c3, t)
  UNIT(i4, i5, i6, i7, c4, c5, c6, c7, t + 512)
#undef UNIT
#undef GJ
#undef BL
#undef BH
}

// ---------------------------------------------------------------------------
extern "C" void kernel_launch(void* const* d_in, const int* in_sizes, int n_in,
                              void* d_out, int out_size, void* d_ws, size_t ws_size,
                              hipStream_t stream) {
  const float* x  = (const float*)d_in[0];   // [4096, 2048]
  const float* W  = (const float*)d_in[1];   // [1024, 2048]
  const float* Dl = (const float*)d_in[2];   // [1024, 2048]
  const float* GN = (const float*)d_in[3];   // [1, 1024, 2048]
  float* y = (float*)d_out;                  // [4096, 1024]

  int*   selCi = (int*)d_ws;                                   // 1024*16 ints
  float* selC  = (float*)((char*)d_ws + UNITS * KCONN * sizeof(int));

  topk_sel_kernel<<<UNITS / 4, 256, 0, stream>>>(Dl, GN, W, selCi, selC);
  gather_mm_kernel<<<BATCH / BB, 512, 0, stream>>>(x, selCi, selC, y);
}

// Round 5
// 26.552 us; speedup vs baseline: 1.7394x; 1.2318x over previous
//
#include <hip/hip_runtime.h>
#include <hip/hip_bf16.h>

#define UNITS 1024
#define DIN   2048
#define KCONN 16
#define BATCH 4096
#define BB    8   // batch rows per tile in kernel 2

typedef float    f32x4 __attribute__((ext_vector_type(4)));
typedef unsigned u32x4 __attribute__((ext_vector_type(4)));
typedef int      i32x4 __attribute__((ext_vector_type(4)));

#define LDNT4F(P) __builtin_nontemporal_load((const f32x4*)(P))

// ---------------------------------------------------------------------------
// Kernel 1: per-unit top-16 of P = D + GN (register-resident), sign(W) fused.
// One wave per unit; P held as 32 VGPRs/lane. Per iteration: DPP wave-argmax
// + owner pop (promote precomputed 2nd max, or rare claim-masked rescan).
// Winner of iteration `it` is wave-uniform (readlane) -> lane `it` keeps it.
// Emits packed selection: (swizzled_chunk << 1) | (W<0), or DIN<<1 if W==0.
// Zero LDS.
// ---------------------------------------------------------------------------
__global__ __launch_bounds__(256) void topk_sel_kernel(
    const float* __restrict__ Dl, const float* __restrict__ GN,
    const float* __restrict__ W, int* __restrict__ selP) {
  const int lane = threadIdx.x & 63;
  const int wv   = threadIdx.x >> 6;
  const int u    = blockIdx.x * 4 + wv;

  // lane owns features g(l) = (l>>2)*256 + lane*4 + (l&3), l = 0..31
  const f32x4* D4 = (const f32x4*)(Dl + (size_t)u * DIN);
  const f32x4* G4 = (const f32x4*)(GN + (size_t)u * DIN);
  float v[32];
#pragma unroll
  for (int i4 = 0; i4 < 8; ++i4) {
    f32x4 d = LDNT4F(D4 + i4 * 64 + lane);
    f32x4 g = LDNT4F(G4 + i4 * 64 + lane);
    v[i4 * 4 + 0] = d[0] + g[0];
    v[i4 * 4 + 1] = d[1] + g[1];
    v[i4 * 4 + 2] = d[2] + g[2];
    v[i4 * 4 + 3] = d[3] + g[3];
  }

  // per-lane top-2 (strict >  => first/lowest-l wins ties)
  float m1 = -INFINITY, m2 = -INFINITY;
  int   l1 = 0, l2 = 0;
#pragma unroll
  for (int l = 0; l < 32; ++l) {
    float xv = v[l];
    bool g1t = xv > m1;
    bool g2t = xv > m2;
    m2 = g1t ? m1 : (g2t ? xv : m2);
    l2 = g1t ? l1 : (g2t ? l : l2);
    m1 = g1t ? xv : m1;
    l1 = g1t ? l  : l1;
  }

  unsigned claimed = 0;
  int navail = 2;        // 2: m1,m2 valid; 1: only m1 valid
  int gsel = 0;          // lane j holds winner-g of iteration j

#pragma unroll 1
  for (int it = 0; it < KCONN; ++it) {
    // monotone u32 key for float compare
    unsigned kb = __float_as_uint(m1);
    unsigned kv = kb ^ (((int)kb < 0) ? 0xFFFFFFFFu : 0x80000000u);
    int g1 = ((l1 >> 2) << 8) | (lane << 2) | (l1 & 3);   // unique per lane
    unsigned rk = kv; int rg = g1;
#define DSTEP(CTRL, RM) { \
    unsigned k2_ = (unsigned)__builtin_amdgcn_update_dpp((int)rk, (int)rk, CTRL, RM, 0xF, false); \
    int g2_ = __builtin_amdgcn_update_dpp(rg, rg, CTRL, RM, 0xF, false); \
    bool tk_ = (k2_ > rk) || ((k2_ == rk) && (g2_ < rg)); \
    rk = tk_ ? k2_ : rk; rg = tk_ ? g2_ : rg; }
    DSTEP(0x111, 0xF)   // row_shr:1
    DSTEP(0x112, 0xF)   // row_shr:2
    DSTEP(0x114, 0xF)   // row_shr:4
    DSTEP(0x118, 0xF)   // row_shr:8
    DSTEP(0x142, 0xA)   // row_bcast:15 -> rows 1,3
    DSTEP(0x143, 0xC)   // row_bcast:31 -> rows 2,3
#undef DSTEP
    int wg = __builtin_amdgcn_readlane(rg, 63);           // wave-uniform winner
    if (lane == it) gsel = wg;                            // lane `it` keeps it

    bool own  = (g1 == wg);
    bool need = own && (navail == 1);                     // must rescan
    if (own) claimed |= 1u << l1;
    if (own && navail == 2) { m1 = m2; l1 = l2; navail = 1; }
    if (need) {                                           // rare: owner rescans regs
      float bm = -INFINITY; int bl = 0;
#pragma unroll
      for (int l = 0; l < 32; ++l) {
        float xv = (claimed & (1u << l)) ? -INFINITY : v[l];
        if (xv > bm) { bm = xv; bl = l; }
      }
      m1 = bm; l1 = bl;
    }
  }

  if (lane < KCONN) {
    int g = gsel;
    float w = W[(size_t)u * DIN + g];
    int sd = g ^ ((g >> 3) & 7);                          // swizzled chunk
    int pa = (w == 0.0f) ? (DIN << 1)
                         : ((sd << 1) | (w < 0.0f ? 1 : 0));
    selP[u * KCONN + lane] = pa;
  }
}

// ---------------------------------------------------------------------------
// Kernel 2: y[b,u] = sum_j sign_j * x[b, idx_j(u)]
// LDS: xs[chunk] = 16B of 8 bf16 batch values per feature (XOR-swizzled),
// plus one zeroed spare chunk (xs[DIN]) targeted by zero-weight selections.
// Packed sel: (chunk<<1)|neg -> sign applied by XOR 0x80008000.
// 512 threads, grid 512; low VGPR so 2 blocks/CU co-reside (stage||gather).
// ---------------------------------------------------------------------------
__global__ __launch_bounds__(512) void gather_mm_kernel(
    const float* __restrict__ x, const int* __restrict__ selP,
    float* __restrict__ y) {
  __shared__ u32x4 xs[DIN + 1];        // 32 KB + 16B
  const int t = threadIdx.x;
  const size_t b0 = (size_t)blockIdx.x * BB;

  // sel prefetch for units t and t+512 (in flight under staging)
  const i32x4* S0 = (const i32x4*)(selP + t * KCONN);
  const i32x4* S1 = (const i32x4*)(selP + (t + 512) * KCONN);
  i32x4 sA0 = S0[0], sA1 = S0[1], sA2 = S0[2], sA3 = S0[3];
  i32x4 sB0 = S1[0], sB1 = S1[1], sB2 = S1[2], sB3 = S1[3];

  // ---- stage: thread t owns features 4t..4t+3, builds whole 16B chunks ----
  const float* xb = x + b0 * DIN + 4 * t;
  f32x4 r0 = LDNT4F(xb + 0 * DIN);
  f32x4 r1 = LDNT4F(xb + 1 * DIN);
  f32x4 r2 = LDNT4F(xb + 2 * DIN);
  f32x4 r3 = LDNT4F(xb + 3 * DIN);
  f32x4 r4 = LDNT4F(xb + 4 * DIN);
  f32x4 r5 = LDNT4F(xb + 5 * DIN);
  f32x4 r6 = LDNT4F(xb + 6 * DIN);
  f32x4 r7 = LDNT4F(xb + 7 * DIN);

#define PK2(LO, HI) ({ __hip_bfloat16 l_ = __float2bfloat16(LO), h_ = __float2bfloat16(HI); \
  (unsigned)(*(unsigned short*)&l_) | ((unsigned)(*(unsigned short*)&h_) << 16); })
#pragma unroll
  for (int j = 0; j < 4; ++j) {
    const int d  = 4 * t + j;
    const int sd = d ^ ((d >> 3) & 7);
    u32x4 ch;
    ch[0] = PK2(r0[j], r1[j]);
    ch[1] = PK2(r2[j], r3[j]);
    ch[2] = PK2(r4[j], r5[j]);
    ch[3] = PK2(r6[j], r7[j]);
    xs[sd] = ch;
  }
#undef PK2
  if (t == 0) { u32x4 z = {0, 0, 0, 0}; xs[DIN] = z; }   // zero-weight sink
  __syncthreads();

  // ---- gather + accumulate ----
#define GJ(PA) { unsigned pa_ = (unsigned)(PA); \
  u32x4 vv_ = xs[pa_ >> 1]; \
  unsigned sm_ = (pa_ & 1u) ? 0x80008000u : 0u; \
  vv_[0] ^= sm_; vv_[1] ^= sm_; vv_[2] ^= sm_; vv_[3] ^= sm_; \
  a0 += __uint_as_float(vv_[0] << 16); a1 += __uint_as_float(vv_[0] & 0xffff0000u); \
  a2 += __uint_as_float(vv_[1] << 16); a3 += __uint_as_float(vv_[1] & 0xffff0000u); \
  a4 += __uint_as_float(vv_[2] << 16); a5 += __uint_as_float(vv_[2] & 0xffff0000u); \
  a6 += __uint_as_float(vv_[3] << 16); a7 += __uint_as_float(vv_[3] & 0xffff0000u); }

#define UNIT(SA, SB, SC, SD, U) { \
  float a0 = 0, a1 = 0, a2 = 0, a3 = 0, a4 = 0, a5 = 0, a6 = 0, a7 = 0; \
  GJ(SA[0]) GJ(SA[1]) GJ(SA[2]) GJ(SA[3]) \
  GJ(SB[0]) GJ(SB[1]) GJ(SB[2]) GJ(SB[3]) \
  GJ(SC[0]) GJ(SC[1]) GJ(SC[2]) GJ(SC[3]) \
  GJ(SD[0]) GJ(SD[1]) GJ(SD[2]) GJ(SD[3]) \
  const int u_ = (U); \
  __builtin_nontemporal_store(a0, &y[(b0 + 0) * UNITS + u_]); \
  __builtin_nontemporal_store(a1, &y[(b0 + 1) * UNITS + u_]); \
  __builtin_nontemporal_store(a2, &y[(b0 + 2) * UNITS + u_]); \
  __builtin_nontemporal_store(a3, &y[(b0 + 3) * UNITS + u_]); \
  __builtin_nontemporal_store(a4, &y[(b0 + 4) * UNITS + u_]); \
  __builtin_nontemporal_store(a5, &y[(b0 + 5) * UNITS + u_]); \
  __builtin_nontemporal_store(a6, &y[(b0 + 6) * UNITS + u_]); \
  __builtin_nontemporal_store(a7, &y[(b0 + 7) * UNITS + u_]); }

  UNIT(sA0, sA1, sA2, sA3, t)
  UNIT(sB0, sB1, sB2, sB3, t + 512)
#undef UNIT
#undef GJ
}

// ---------------------------------------------------------------------------
extern "C" void kernel_launch(void* const* d_in, const int* in_sizes, int n_in,
                              void* d_out, int out_size, void* d_ws, size_t ws_size,
                              hipStream_t stream) {
  const float* x  = (const float*)d_in[0];   // [4096, 2048]
  const float* W  = (const float*)d_in[1];   // [1024, 2048]
  const float* Dl = (const float*)d_in[2];   // [1024, 2048]
  const float* GN = (const float*)d_in[3];   // [1, 1024, 2048]
  float* y = (float*)d_out;                  // [4096, 1024]

  int* selP = (int*)d_ws;                    // 1024*16 packed ints

  topk_sel_kernel<<<UNITS / 4, 256, 0, stream>>>(Dl, GN, W, selP);
  gather_mm_kernel<<<BATCH / BB, 512, 0, stream>>>(x, selP, y);
}